// Round 1
// baseline (345.035 us; speedup 1.0000x reference)
//
#include <hip/hip_runtime.h>
#include <math.h>

// Problem constants (from reference)
#define PN 32
#define PM 100
#define PK 500
#define PE 50

static constexpr float DEG2RAD = 0.017453292519943295f; // pi/180
static constexpr float TWO_R   = 2.0f * 6371.0f;

// out[n,m,k,e] = C[n,m,e] + ds[n,m,k] * D[n,m,e]
//   C[e] = esl[i][e] + (etl[i][e]*(500-dt) + etu[i][e]*dt) * (1/500)
//   D[e] = (esu[i][e] - esl[i][e]) * (1/1000)
//   i = (m < traj_len[n]) ? 1 : 0, dt = vec[n,m]
//   ds = 2*R*asin(sqrt(clip(hav,0,1)))
__global__ __launch_bounds__(256) void embed_kernel(
    const int*   __restrict__ traj_loc,  // N*M
    const float* __restrict__ poi,       // LOC*2
    const float* __restrict__ vec,       // N*M
    const int*   __restrict__ traj_len,  // N
    const int*   __restrict__ cand,      // N*K
    const float* __restrict__ emb_su,    // 2*E
    const float* __restrict__ emb_sl,    // 2*E
    const float* __restrict__ emb_tu,    // 2*E
    const float* __restrict__ emb_tl,    // 2*E
    float*       __restrict__ out)       // N*M*K*E
{
    const int nm  = blockIdx.x;        // 0 .. N*M-1
    const int n   = nm / PM;
    const int m   = nm - n * PM;
    const int tid = threadIdx.x;

    __shared__ float s_ds[PK];
    __shared__ float s_C[PE];
    __shared__ float s_D[PE];

    // --- per-(n,m) uniform values (scalar loads: addresses are tid-independent)
    const int   tl   = traj_loc[nm];
    const float lat1 = poi[2 * tl]     * DEG2RAD;
    const float lon1 = poi[2 * tl + 1] * DEG2RAD;
    const float coslat1 = __cosf(lat1);

    // --- stage C[e], D[e]
    if (tid < PE) {
        const int   i  = (m < traj_len[n]) ? 1 : 0;
        const float dt = vec[nm];
        const float esl = emb_sl[i * PE + tid];
        const float esu = emb_su[i * PE + tid];
        const float etl = emb_tl[i * PE + tid];
        const float etu = emb_tu[i * PE + tid];
        s_C[tid] = esl + (etl * (500.0f - dt) + etu * dt) * (1.0f / 500.0f);
        s_D[tid] = (esu - esl) * (1.0f / 1000.0f);
    }

    // --- stage ds[k]: haversine distance traj(n,m) -> cand(n,k)
    for (int k = tid; k < PK; k += 256) {
        const int   cl   = cand[n * PK + k];
        const float lat2 = poi[2 * cl]     * DEG2RAD;
        const float lon2 = poi[2 * cl + 1] * DEG2RAD;
        const float sdlat = __sinf(0.5f * (lat2 - lat1));
        const float sdlon = __sinf(0.5f * (lon2 - lon1));
        float a = sdlat * sdlat + coslat1 * __cosf(lat2) * (sdlon * sdlon);
        a = fminf(fmaxf(a, 0.0f), 1.0f);
        s_ds[k] = TWO_R * asinf(sqrtf(a));
    }

    __syncthreads();

    // --- stream the output: K*E = 25000 floats = 6250 float4 per (n,m)
    float4* __restrict__ out4 =
        reinterpret_cast<float4*>(out + (size_t)nm * (PK * PE));
    constexpr int NV = (PK * PE) / 4;  // 6250

    for (int t = tid; t < NV; t += 256) {
        const unsigned f = (unsigned)t * 4u;
        unsigned k = f / (unsigned)PE;        // magic-mul division by 50
        unsigned e = f - k * (unsigned)PE;
        float ds = s_ds[k];
        float4 v;
        v.x = fmaf(ds, s_D[e], s_C[e]);
        if (++e == PE) { e = 0; ds = s_ds[++k]; }
        v.y = fmaf(ds, s_D[e], s_C[e]);
        if (++e == PE) { e = 0; ds = s_ds[++k]; }
        v.z = fmaf(ds, s_D[e], s_C[e]);
        if (++e == PE) { e = 0; ds = s_ds[++k]; }
        v.w = fmaf(ds, s_D[e], s_C[e]);
        out4[t] = v;
    }
}

extern "C" void kernel_launch(void* const* d_in, const int* in_sizes, int n_in,
                              void* d_out, int out_size, void* d_ws, size_t ws_size,
                              hipStream_t stream) {
    const int*   traj_loc = (const int*)  d_in[0];
    const float* poi      = (const float*)d_in[1];
    const float* vec      = (const float*)d_in[2];
    const int*   traj_len = (const int*)  d_in[3];
    const int*   cand     = (const int*)  d_in[4];
    const float* emb_su   = (const float*)d_in[5];
    const float* emb_sl   = (const float*)d_in[6];
    const float* emb_tu   = (const float*)d_in[7];
    const float* emb_tl   = (const float*)d_in[8];
    float* out = (float*)d_out;

    dim3 grid(PN * PM);   // 3200 blocks, one per (n,m)
    dim3 block(256);
    embed_kernel<<<grid, block, 0, stream>>>(
        traj_loc, poi, vec, traj_len, cand,
        emb_su, emb_sl, emb_tu, emb_tl, out);
}